// Round 17
// baseline (18.684 us; speedup 1.0000x reference)
//
#include <hip/hip_runtime.h>

// NodeCycleFeatures via MFMA, 4 waves/batch (R16 base) + fused linear row-pass.
// B=2048, N=64, A = E[...,1] symmetric 0/1, zero diag.
// Phase L writes A-bf16 DIRECTLY into LDS (bf16(A)=top 16 bits of f32, exact)
// while building mask slices; mask assembly rides in the MFMA shadow.
// Wave w owns MFMA tile (R,C)=(w>>1,w&1) of k2=A@A and k3=k2@A
// (v_mfma_f32_32x32x16_bf16; integer-exact). C/D layout (verified R8-R16):
// col=lane&31, row=(reg&3)+8*(reg>>2)+4*(lane>>5). k2/k3 col-major
// (== row-major by symmetry), 16B-block XOR swizzle. 4 barriers.
// Row-pass fused into 3 linear accumulators (row-uniform coefficients known
// pre-loop): u=Σk2(k2-1), v=Σ(k2·k3-A·c3), wq=Σ[k3(k3+3)+k2²(bit?15-6di:6-6di)]
// -> c4,c5,c6 recovered per-row; butterfly 14->6 shuffles.

typedef __attribute__((ext_vector_type(8))) short bf16x8;
typedef __attribute__((ext_vector_type(16))) float f32x16;

constexpr int BATCH = 2048;
constexpr int NN = 64;

__device__ __forceinline__ bf16x8 frag_ld(const unsigned short* buf, int row, int kb2) {
  const int idx = row * 64 + ((kb2 ^ (row & 7)) << 3);  // 16B-block swizzle
  const uint4 v = *reinterpret_cast<const uint4*>(buf + idx);
  union { uint4 u; bf16x8 b; } cv; cv.u = v; return cv.b;
}

__global__ __launch_bounds__(256, 8) void node_cycle_kernel(
    const float4* __restrict__ E4,   // [B,N,N,2] floats viewed as float4
    const float* __restrict__ nmask, // [B,N]
    float* __restrict__ out)         // x: [B,N,3] then y: [B,4]
{
  const int b = blockIdx.x;
  const int tid = threadIdx.x;
  const int lane = tid & 63;
  const int w = tid >> 6;            // wave id 0..3
  const int h = lane >> 5;           // lane half (MFMA k-half)
  const int c31 = lane & 31;
  const int R = w >> 1, C = w & 1;   // this wave's MFMA tile

  __shared__ unsigned short bufA[64 * 64];   // A bf16; reused for k3 (u16)
  __shared__ unsigned short bufK2[64 * 64];  // k2 bf16 (col-major == row-major)
  __shared__ unsigned short sl[4][64];       // per-wave 16-bit col-mask slices
  __shared__ uint2 rms[NN];                  // full row masks
  __shared__ float c3sh[NN];
  __shared__ float4 gpart[4];                // per-wave graph-sum partials

  const float4* __restrict__ Eb = E4 + (size_t)b * (NN * NN / 2);

  // Row-pass ownership: wave w rows [16w,16w+16), 4 lanes per row.
  const int rp_r = 16 * w + (lane >> 2);
  const int rp_q = lane & 3;
  const float m_r = nmask[b * NN + rp_r];    // early scalar global load

  // ---- Phase L: load rows [16w,16w+16); write A-bf16 directly (swizzled) and
  // build 16-bit column-mask slices. float4 i=w*512+q*64+lane: row=16w+2q+h,
  // cols 2*c31 (.y) and 2*c31+1 (.w). bf16 = top half of f32 (0/1 exact).
  const int cb = c31 >> 2;          // 16B block index (8 cols/block)
  const int co = (c31 & 3) * 2;     // u16 offset within block
  unsigned mA = 0u, mB = 0u;
  #pragma unroll
  for (int q = 0; q < 8; ++q) {
    const float4 f = Eb[w * 512 + q * 64 + lane];
    const int row = 16 * w + 2 * q + h;
    const unsigned word = (__float_as_uint(f.y) >> 16) |
                          (__float_as_uint(f.w) & 0xFFFF0000u);
    *reinterpret_cast<unsigned*>(
        &bufA[row * 64 + ((cb ^ (row & 7)) << 3) + co]) = word;
    const int bit = 2 * q + h;
    mA |= (unsigned)(f.y > 0.5f) << bit;
    mB |= (unsigned)(f.w > 0.5f) << bit;
  }
  mA |= (unsigned)__shfl_xor((int)mA, 32);
  mB |= (unsigned)__shfl_xor((int)mB, 32);
  if (lane < 32) {
    sl[w][2 * lane]     = (unsigned short)mA;
    sl[w][2 * lane + 1] = (unsigned short)mB;
  }
  __syncthreads();                                    // B1: A + slices ready

  // ---- Mask assembly rides in the MFMA shadow (first read is post-B3) ----
  if (tid < 128) {
    const int c = tid >> 1, hf = tid & 1;
    const unsigned v = (unsigned)sl[2 * hf][c] | ((unsigned)sl[2 * hf + 1][c] << 16);
    if (hf == 0) rms[c].x = v; else rms[c].y = v;
  }

  // ---- m1: k2 tile (R,C). Bf hoisted (reused by m2); Af staged per-K ----
  bf16x8 Bf[4];
  #pragma unroll
  for (int K = 0; K < 4; ++K) Bf[K] = frag_ld(bufA, C * 32 + c31, 2 * K + h);

  f32x16 acc;
  #pragma unroll
  for (int r = 0; r < 16; ++r) acc[r] = 0.f;
  #pragma unroll
  for (int K = 0; K < 4; ++K) {
    const bf16x8 af = frag_ld(bufA, R * 32 + c31, 2 * K + h);
    acc = __builtin_amdgcn_mfma_f32_32x32x16_bf16(af, Bf[K], acc, 0, 0, 0);
  }

  // ---- Pack k2 tile -> bufK2 col-major bf16 (regs 4g..4g+3 = 4 rows) ----
  {
    const int c = C * 32 + c31;
    #pragma unroll
    for (int g = 0; g < 4; ++g) {
      const unsigned w0 = (__float_as_uint(acc[4*g+1]) & 0xffff0000u) |
                          (__float_as_uint(acc[4*g+0]) >> 16);
      const unsigned w1 = (__float_as_uint(acc[4*g+3]) & 0xffff0000u) |
                          (__float_as_uint(acc[4*g+2]) >> 16);
      const int bb = (4 * R + g) ^ (c & 7);
      *reinterpret_cast<uint2*>(&bufK2[c * 64 + bb * 8 + h * 4]) = make_uint2(w0, w1);
    }
  }
  __syncthreads();                                    // B2: k2 ready, bufA reads done

  // ---- m2: k3 tile (R,C) = k2[R] @ A[C] (Kf staged per-K, Bf in regs) ----
  f32x16 d;
  #pragma unroll
  for (int r = 0; r < 16; ++r) d[r] = 0.f;
  #pragma unroll
  for (int K = 0; K < 4; ++K) {
    const bf16x8 kf = frag_ld(bufK2, R * 32 + c31, 2 * K + h);
    d = __builtin_amdgcn_mfma_f32_32x32x16_bf16(kf, Bf[K], d, 0, 0, 0);
  }

  // ---- c3 = diag(k3): diagonal tiles only ----
  if (R == C) {
    const int dtarget = c31 - 4 * h;
    float c3d = 0.f;
    #pragma unroll
    for (int r = 0; r < 16; ++r) {
      const int rowbase = (r & 3) + 8 * (r >> 2);
      c3d += (rowbase == dtarget) ? d[r] : 0.f;
    }
    if (((c31 >> 2) & 1) == h) c3sh[R * 32 + c31] = c3d;
  }

  // ---- Pack k3 tile -> bufA as u16 (k3 <= 3844 exact; no bufA reads post-B2) ----
  {
    const int c = C * 32 + c31;
    #pragma unroll
    for (int g = 0; g < 4; ++g) {
      const unsigned u0 = ((unsigned)d[4*g+0]) | (((unsigned)d[4*g+1]) << 16);
      const unsigned u1 = ((unsigned)d[4*g+2]) | (((unsigned)d[4*g+3]) << 16);
      const int bb = (4 * R + g) ^ (c & 7);
      *reinterpret_cast<uint2*>(&bufA[c * 64 + bb * 8 + h * 4]) = make_uint2(u0, u1);
    }
  }
  __syncthreads();                                    // B3: k3 + c3 + rms ready

  // ---- Row-pass: lane -> (row rp_r, col-quarter rp_q), 16 cols/lane ----
  // Fused accumulators (row-uniform coefficients precomputed):
  //   u  = sum k2*(k2-1)                       -> c4 = u - di*(di-1)
  //   v  = sum (k2*k3 - A*c3)                  -> c5 = v - 2*c3i*di + c3i
  //   wq = sum [k3*(k3+3) + k2^2*(A?15-6di:6-6di)]
  //        (= t1 + 3*t8 + 9*t3 + (6-6di)*diag4)
  const uint2 mr = rms[rp_r];                         // 4-lane broadcast
  const float di = (float)(__popc(mr.x) + __popc(mr.y));
  const float cf0 = 6.f - 6.f * di;                   // k2^2 coef, A-bit = 0
  const float cf1 = 15.f - 6.f * di;                  // k2^2 coef, A-bit = 1
  float u = 0.f, v = 0.f, wq = 0.f;
  #pragma unroll
  for (int e = 0; e < 2; ++e) {
    const int bq = 2 * rp_q + e;
    const int idx = rp_r * 64 + ((bq ^ (rp_r & 7)) << 3);
    const uint4 vk2 = *reinterpret_cast<const uint4*>(&bufK2[idx]);
    const uint4 vk3 = *reinterpret_cast<const uint4*>(&bufA[idx]);
    const float4 c3a = *reinterpret_cast<const float4*>(&c3sh[bq * 8]);
    const float4 c3b = *reinterpret_cast<const float4*>(&c3sh[bq * 8 + 4]);
    const unsigned wk2[4] = {vk2.x, vk2.y, vk2.z, vk2.w};
    const unsigned wk3[4] = {vk3.x, vk3.y, vk3.z, vk3.w};
    const float c3v[8] = {c3a.x, c3a.y, c3a.z, c3a.w, c3b.x, c3b.y, c3b.z, c3b.w};
    #pragma unroll
    for (int e2 = 0; e2 < 4; ++e2) {
      const int j0 = bq * 8 + 2 * e2;
      const float k2lo = __uint_as_float(wk2[e2] << 16);
      const float k2hi = __uint_as_float(wk2[e2] & 0xffff0000u);
      const float k3lo = (float)(wk3[e2] & 0xffffu);
      const float k3hi = (float)(wk3[e2] >> 16);
      const unsigned b0 = (j0 < 32 ? (mr.x >> j0) : (mr.y >> (j0 - 32))) & 1u;
      const unsigned b1 = ((j0 + 1) < 32 ? (mr.x >> (j0 + 1)) : (mr.y >> (j0 + 1 - 32))) & 1u;
      u = fmaf(k2lo, k2lo - 1.f, fmaf(k2hi, k2hi - 1.f, u));
      v = fmaf(k2lo, k3lo, fmaf(k2hi, k3hi, v))
        - (b0 ? c3v[2 * e2] : 0.f) - (b1 ? c3v[2 * e2 + 1] : 0.f);
      wq = fmaf(k3lo, k3lo + 3.f, fmaf(k3hi, k3hi + 3.f, wq));
      wq = fmaf(k2lo * k2lo, b0 ? cf1 : cf0,
           fmaf(k2hi * k2hi, b1 ? cf1 : cf0, wq));
    }
  }
  // 2-level butterfly over the 4 quarter-lanes of each row (3 values)
  #pragma unroll
  for (int off = 1; off <= 2; off <<= 1) {
    u  += __shfl_xor(u, off);
    v  += __shfl_xor(v, off);
    wq += __shfl_xor(wq, off);
  }

  // ---- Per-row quantities (all 4 lanes of a row hold full-row values) ----
  const float c3i = c3sh[rp_r];
  const float c4 = u - di * (di - 1.f);
  const float c5 = v - 2.f * c3i * di + c3i;
  const float c6p = wq - 3.f * (c3i * c3i) - 4.f * c3i
                  + 4.f * (di * di * di) - 12.f * (di * di) + 4.f * di;

  // ---- x outputs: one lane per row ----
  if (rp_q == 0) {
    float* xo = out + ((size_t)b * NN + rp_r) * 3;
    xo[0] = fminf(c3i * 0.05f * m_r, 1.f);
    xo[1] = fminf(c4  * 0.05f * m_r, 1.f);
    xo[2] = fminf(c5  * 0.05f * m_r, 1.f);
  }

  // ---- Graph sums: lanes l, l+4, ..., l+60 are 16 distinct rows ----
  float sc3 = c3i, sc4 = c4, sc5 = c5, sc6 = c6p;
  #pragma unroll
  for (int off = 4; off < 64; off <<= 1) {
    sc3 += __shfl_xor(sc3, off);
    sc4 += __shfl_xor(sc4, off);
    sc5 += __shfl_xor(sc5, off);
    sc6 += __shfl_xor(sc6, off);
  }
  if (lane == 0) gpart[w] = make_float4(sc3, sc4, sc5, sc6);
  __syncthreads();                                    // B4

  if (tid == 0) {
    const float4 g0 = gpart[0], g1 = gpart[1], g2 = gpart[2], g3 = gpart[3];
    float4 y;
    y.x = fminf((g0.x + g1.x + g2.x + g3.x) * (1.f / 6.f)  * 0.1f, 1.f);
    y.y = fminf((g0.y + g1.y + g2.y + g3.y) * (1.f / 8.f)  * 0.1f, 1.f);
    y.z = fminf((g0.z + g1.z + g2.z + g3.z) * (1.f / 10.f) * 0.1f, 1.f);
    y.w = fminf((g0.w + g1.w + g2.w + g3.w) * (1.f / 12.f) * 0.1f, 1.f);
    *reinterpret_cast<float4*>(out + (size_t)BATCH * NN * 3 + b * 4) = y;
  }
}

extern "C" void kernel_launch(void* const* d_in, const int* in_sizes, int n_in,
                              void* d_out, int out_size, void* d_ws, size_t ws_size,
                              hipStream_t stream) {
  const float4* E4 = reinterpret_cast<const float4*>(d_in[0]);
  const float* nmask = reinterpret_cast<const float*>(d_in[1]);
  float* out = reinterpret_cast<float*>(d_out);
  node_cycle_kernel<<<BATCH, 256, 0, stream>>>(E4, nmask, out);
}